// Round 10
// baseline (207.928 us; speedup 1.0000x reference)
//
#include <hip/hip_runtime.h>

#define HIDDEN 256
#define CAP 64   // bucket capacity per node; deg ~ Poisson(16) => P(deg>=64) ~ e^-40

typedef _Float16 h4_t __attribute__((ext_vector_type(4)));
typedef _Float16 h8_t __attribute__((ext_vector_type(8)));
typedef float    f4_t __attribute__((ext_vector_type(4)));

typedef const __attribute__((address_space(1))) void* gbl_ptr_t;
typedef __attribute__((address_space(3))) void*       lds_ptr_t;

__device__ inline f4_t cvt4(h4_t h) {
    f4_t o; o.x = (float)h.x; o.y = (float)h.y; o.z = (float)h.z; o.w = (float)h.w;
    return o;
}

// ---------------- fused prep ---------------------------------------------------------
// Block groups: [x->f16 prelu (NO mask)] [csr fill (+nothing)] [W1/W2 -> f16]
// [Wc = W1 @ W_enc -> B_cat left half] [mask flags]
__global__ __launch_bounds__(256) void k_prep(
        const float* __restrict__ x, _Float16* __restrict__ xh,
        const float* __restrict__ prelu_a, int M, int Mpad, int nb_x,
        const int* __restrict__ ei, const int* __restrict__ ea, int E,
        int* __restrict__ cnt, int* __restrict__ csr, int nb_fill,
        const float* __restrict__ W1, const float* __restrict__ W2,
        _Float16* __restrict__ Bcat, _Float16* __restrict__ Wh2, int nb_w,
        const float* __restrict__ W_enc, int nb_wc,
        const int* __restrict__ mask, unsigned char* __restrict__ flags, int NM) {
    __shared__ float W1s[8 * HIDDEN];   // for the Wc branch (8 KB)
    int b = blockIdx.x;
    int t = threadIdx.x;
    if (b < nb_x) {
        int base = (b * 256 + t) * 4;
        if (base >= Mpad * HIDDEN) return;
        int row = base >> 8;
        h4_t o;
        if (row < M) {
            float pa = *prelu_a;
            f4_t v = *(const f4_t*)(x + base);
            o.x = (_Float16)(v.x >= 0.f ? v.x : pa * v.x);
            o.y = (_Float16)(v.y >= 0.f ? v.y : pa * v.y);
            o.z = (_Float16)(v.z >= 0.f ? v.z : pa * v.z);
            o.w = (_Float16)(v.w >= 0.f ? v.w : pa * v.w);
        } else {
            o = (h4_t)(_Float16)0.f;
        }
        *(h4_t*)(xh + base) = o;
        return;
    }
    b -= nb_x;
    if (b < nb_fill) {
        int e = b * 256 + t;
        if (e >= E) return;
        int src = ei[e];
        int dst = ei[E + e];
        int combo = ea[2 * e] * 3 + ea[2 * e + 1];     // a1*3+a2, 0..17
        int slot = atomicAdd(&cnt[dst], 1);
        if (slot < CAP) csr[dst * CAP + slot] = src | (combo << 16);
        return;
    }
    b -= nb_fill;
    if (b < nb_w) {
        const int n1 = 2 * HIDDEN * HIDDEN;            // W1 elems (512x256)
        const int n2 = HIDDEN * 2 * HIDDEN;            // W2 elems (256x512)
        int base = (b * 256 + t) * 4;
        if (base < n1) {
            // W1[row][col] -> Bcat[row][256+col] (row stride 512)
            int row = base >> 8, col = base & 255;
            f4_t v = *(const f4_t*)(W1 + base);
            h4_t o; o.x = (_Float16)v.x; o.y = (_Float16)v.y;
            o.z = (_Float16)v.z; o.w = (_Float16)v.w;
            *(h4_t*)(Bcat + (size_t)row * 512 + 256 + col) = o;
        } else if (base < n1 + n2) {
            int off = base - n1;
            f4_t v = *(const f4_t*)(W2 + off);
            h4_t o; o.x = (_Float16)v.x; o.y = (_Float16)v.y;
            o.z = (_Float16)v.z; o.w = (_Float16)v.w;
            *(h4_t*)(Wh2 + off) = o;
        }
        return;
    }
    b -= nb_w;
    if (b < nb_wc) {
        // Wc[n][k] = sum_c W1[n][c] * W_enc[c][k]; rows n0..n0+7 -> Bcat[n][k]
        int n0 = b * 8;
        for (int i = t; i < 8 * HIDDEN; i += 256) W1s[i] = W1[n0 * HIDDEN + i];
        __syncthreads();
        int k = t;                                     // 0..255
        float acc[8] = {};
        for (int c = 0; c < HIDDEN; ++c) {
            float we = W_enc[c * HIDDEN + k];
#pragma unroll
            for (int r = 0; r < 8; ++r) acc[r] += W1s[r * HIDDEN + c] * we;
        }
#pragma unroll
        for (int r = 0; r < 8; ++r)
            Bcat[(size_t)(n0 + r) * 512 + k] = (_Float16)acc[r];
        return;
    }
    b -= nb_wc;
    {
        int i = b * 256 + t;
        if (i < NM) flags[mask[i]] = 1;
    }
}

// ---------------- aggregation in xp space: writes A_cat = [S | esum] -----------------
// S[i] = xp[i]*(1-flag[i]) + sum_src xp[src]*(1-flag[src]); esum[i] = sum e12 + self.
// 4 nodes / 256-thr block; csr+flag preloaded 1/lane, shfl-broadcast, 8-wide gather.
__global__ __launch_bounds__(256) void k_aggregate(
        const _Float16* __restrict__ xp,
        const float* __restrict__ E1, const float* __restrict__ E2,
        const int* __restrict__ cnt, const int* __restrict__ csr,
        const unsigned char* __restrict__ flags,
        _Float16* __restrict__ Acat, int N, int Mpad) {
    __shared__ __align__(16) _Float16 e12h[18 * HIDDEN];   // 9 KB
    int t = threadIdx.x;
    for (int idx = t; idx < 18 * 64; idx += 256) {
        int combo = idx >> 6, c4 = (idx & 63) * 4;
        int a1 = combo / 3, a2 = combo - a1 * 3;
        f4_t v1 = *(const f4_t*)(E1 + a1 * HIDDEN + c4);
        f4_t v2 = *(const f4_t*)(E2 + a2 * HIDDEN + c4);
        h4_t o;
        o.x = (_Float16)(v1.x + v2.x); o.y = (_Float16)(v1.y + v2.y);
        o.z = (_Float16)(v1.z + v2.z); o.w = (_Float16)(v1.w + v2.w);
        *(h4_t*)(e12h + combo * HIDDEN + c4) = o;
    }
    __syncthreads();
    int node = blockIdx.x * 4 + (t >> 6);
    if (node >= Mpad) return;
    int lane = t & 63;
    int c0 = lane * 4;
    const h4_t hz = (h4_t)(_Float16)0.f;
    if (node >= N) {
        *(h4_t*)(Acat + (size_t)node * 512 + c0) = hz;
        *(h4_t*)(Acat + (size_t)node * 512 + 256 + c0) = hz;
        return;
    }
    int deg = cnt[node];
    if (deg > CAP) deg = CAP;
    const int* lst = csr + (size_t)node * CAP;
    int pv = 0;
    if (lane < deg) {
        pv = lst[lane];
        pv |= ((int)flags[pv & 0xFFFF]) << 21;   // pack mask bit (combo uses 16..20)
    }

    h4_t hs = *(const h4_t*)(xp + (size_t)node * HIDDEN + c0);
    if (flags[node]) hs = hz;                    // masked self row
    f4_t accS = cvt4(hs);
    f4_t accE = cvt4(*(const h4_t*)(e12h + 12 * HIDDEN + c0));  // self-loop E1[4]+E2[0]

    int e = 0;
    for (; e + 7 < deg; e += 8) {
        int p[8]; h4_t hv[8], qv[8];
#pragma unroll
        for (int j = 0; j < 8; ++j) p[j] = __shfl(pv, e + j, 64);
#pragma unroll
        for (int j = 0; j < 8; ++j) {
            h4_t h = *(const h4_t*)(xp + (size_t)(p[j] & 0xFFFF) * HIDDEN + c0);
            hv[j] = (p[j] >> 21) ? hz : h;       // masked src contributes 0 to S
        }
#pragma unroll
        for (int j = 0; j < 8; ++j)
            qv[j] = *(const h4_t*)(e12h + ((p[j] >> 16) & 0x1F) * HIDDEN + c0);
        h4_t s0 = (hv[0] + hv[1]) + (hv[2] + hv[3]);
        h4_t s1 = (hv[4] + hv[5]) + (hv[6] + hv[7]);
        h4_t q0 = (qv[0] + qv[1]) + (qv[2] + qv[3]);
        h4_t q1 = (qv[4] + qv[5]) + (qv[6] + qv[7]);
        accS += cvt4(s0) + cvt4(s1);
        accE += cvt4(q0) + cvt4(q1);
    }
    for (; e < deg; ++e) {
        int p = __shfl(pv, e, 64);
        h4_t h = *(const h4_t*)(xp + (size_t)(p & 0xFFFF) * HIDDEN + c0);
        if (p >> 21) h = hz;
        h4_t q = *(const h4_t*)(e12h + ((p >> 16) & 0x1F) * HIDDEN + c0);
        accS += cvt4(h);
        accE += cvt4(q);
    }
    h4_t oS, oE;
    oS.x = (_Float16)accS.x; oS.y = (_Float16)accS.y;
    oS.z = (_Float16)accS.z; oS.w = (_Float16)accS.w;
    oE.x = (_Float16)accE.x; oE.y = (_Float16)accE.y;
    oE.z = (_Float16)accE.z; oE.w = (_Float16)accE.w;
    *(h4_t*)(Acat + (size_t)node * 512 + c0) = oS;
    *(h4_t*)(Acat + (size_t)node * 512 + 256 + c0) = oE;
}

// ---------------- single-wave depth-2 pipelined MFMA GEMM ---------------------------
// 64-thread (1-wave) blocks, tile BM(=TM*16) x 64, BK=32, double-buffered LDS.
// Stages 0,1 pre-issued; at step s wait vmcnt(LPS) (in-order completion => tile s
// landed, tile s+1 still in flight); refill freed buffer before the MFMAs.
template <int TM, int K, bool RELU, bool HAS_BIAS, bool OUT_F16>
__global__ __launch_bounds__(64) void k_gemm64(
        const _Float16* __restrict__ A, const _Float16* __restrict__ B,
        const float* __restrict__ bias, void* __restrict__ Cout,
        int Mstore, int N) {
    constexpr int BM = TM * 16;
    constexpr int LPS = TM + 4;                      // loads per stage
    __shared__ __align__(16) _Float16 As[2][BM * 32];
    __shared__ __align__(16) _Float16 Bs[2][64 * 32];
    int L = threadIdx.x;
    int m0 = blockIdx.x * BM, n0 = blockIdx.y * 64;
    int lr = L & 15, lk = (L >> 4) * 8;

    f4_t acc[TM][4] = {};

    auto stage = [&](int k0, int buf) {
#pragma unroll
        for (int i = 0; i < TM; ++i) {          // A: TM*64 16B chunks
            int c = L + 64 * i;
            __builtin_amdgcn_global_load_lds(
                (gbl_ptr_t)(A + (size_t)(m0 + (c >> 2)) * K + k0 + (c & 3) * 8),
                (lds_ptr_t)(&As[buf][c * 8]), 16, 0, 0);
        }
#pragma unroll
        for (int i = 0; i < 4; ++i) {           // B: 256 chunks
            int c = L + 64 * i;
            __builtin_amdgcn_global_load_lds(
                (gbl_ptr_t)(B + (size_t)(n0 + (c >> 2)) * K + k0 + (c & 3) * 8),
                (lds_ptr_t)(&Bs[buf][c * 8]), 16, 0, 0);
        }
    };

    constexpr int NS = K / 32;
    stage(0, 0);
    if (NS > 1) stage(32, 1);
#pragma unroll
    for (int s = 0; s < NS; ++s) {
        int buf = s & 1;
        if (s + 1 < NS) {
            asm volatile("s_waitcnt vmcnt(%0)" :: "i"(LPS) : "memory");
        } else {
            asm volatile("s_waitcnt vmcnt(0)" ::: "memory");
        }
        h8_t af[TM], bf[4];
#pragma unroll
        for (int i = 0; i < TM; ++i) af[i] = *(const h8_t*)&As[buf][(i * 16 + lr) * 32 + lk];
#pragma unroll
        for (int j = 0; j < 4; ++j)  bf[j] = *(const h8_t*)&Bs[buf][(j * 16 + lr) * 32 + lk];
        asm volatile("s_waitcnt lgkmcnt(0)" ::: "memory"); // frags in regs; buf reusable
        if (s + 2 < NS) stage((s + 2) * 32, buf);
#pragma unroll
        for (int i = 0; i < TM; ++i)
#pragma unroll
            for (int j = 0; j < 4; ++j)
                acc[i][j] = __builtin_amdgcn_mfma_f32_16x16x32_f16(af[i], bf[j], acc[i][j], 0, 0, 0);
    }

    // epilogue: C/D layout col = L&15, row = (L>>4)*4 + r
    int lr4 = (L >> 4) * 4;
#pragma unroll
    for (int i = 0; i < TM; ++i)
#pragma unroll
        for (int r = 0; r < 4; ++r) {
            int row = m0 + i * 16 + lr4 + r;
#pragma unroll
            for (int j = 0; j < 4; ++j) {
                int col = n0 + j * 16 + lr;
                float v = acc[i][j][r];
                if (HAS_BIAS) v += bias[col];
                if (RELU) v = v > 0.f ? v : 0.f;
                if (OUT_F16) {
                    ((_Float16*)Cout)[(size_t)row * N + col] = (_Float16)v;
                } else {
                    if (row < Mstore) ((float*)Cout)[(size_t)row * N + col] = v;
                }
            }
        }
}

extern "C" void kernel_launch(void* const* d_in, const int* in_sizes, int n_in,
                              void* d_out, int out_size, void* d_ws, size_t ws_size,
                              hipStream_t stream) {
    const float* x       = (const float*)d_in[0];
    const int*   ei      = (const int*)d_in[1];
    const int*   ea      = (const int*)d_in[2];
    const int*   mask    = (const int*)d_in[3];
    const float* prelu_a = (const float*)d_in[4];
    const float* W_enc   = (const float*)d_in[5];
    const float* E1      = (const float*)d_in[6];
    const float* E2      = (const float*)d_in[7];
    const float* W1      = (const float*)d_in[8];
    const float* b1      = (const float*)d_in[9];
    const float* W2      = (const float*)d_in[10];
    const float* b2      = (const float*)d_in[11];
    float*       out     = (float*)d_out;

    int N  = in_sizes[0] / HIDDEN;           // 20000
    int E  = in_sizes[1] / 2;                // 320000
    int NM = in_sizes[3];                    // 2000
    int Mpad = ((N + 127) / 128) * 128;      // 20096 (multiple of 32 and 64)

    char* ws = (char*)d_ws;
    size_t off = 0;
    _Float16* xh   = (_Float16*)(ws + off); off += (size_t)Mpad * HIDDEN * 2;
    _Float16* Acat = (_Float16*)(ws + off); off += (size_t)Mpad * 512 * 2;
    _Float16* Hh   = (_Float16*)(ws + off); off += (size_t)Mpad * 512 * 2;
    _Float16* Bcat = (_Float16*)(ws + off); off += (size_t)512 * 512 * 2;
    _Float16* Wh2  = (_Float16*)(ws + off); off += (size_t)HIDDEN * 512 * 2;
    int* cnt       = (int*)(ws + off);      off += (size_t)N * 4;
    unsigned char* flags = (unsigned char*)(ws + off); off += (size_t)Mpad;
    off = (off + 15) & ~(size_t)15;
    int* csr       = (int*)(ws + off);      off += (size_t)N * CAP * 4;

    hipMemsetAsync(cnt, 0, (size_t)N * 4 + (size_t)Mpad, stream);   // cnt + flags

    int nb_x    = (Mpad * HIDDEN / 4 + 255) / 256;   // 5024
    int nb_fill = (E + 255) / 256;                   // 1250
    int wtot4   = (2 * HIDDEN * HIDDEN + HIDDEN * 2 * HIDDEN) / 4;
    int nb_w    = (wtot4 + 255) / 256;               // 256
    int nb_wc   = 512 / 8;                           // 64
    int nb_m    = (NM + 255) / 256;                  // 8
    k_prep<<<nb_x + nb_fill + nb_w + nb_wc + nb_m, 256, 0, stream>>>(
        x, xh, prelu_a, N, Mpad, nb_x,
        ei, ea, E, cnt, csr, nb_fill,
        W1, W2, Bcat, Wh2, nb_w,
        W_enc, nb_wc,
        mask, flags, NM);

    k_aggregate<<<(Mpad + 3) / 4, 256, 0, stream>>>(
        xh, E1, E2, cnt, csr, flags, Acat, N, Mpad);

    // GEMM_H: H = relu([S|esum] @ [Wc|W1]^T + b1). M=20096, N=512, K=512.
    dim3 g2(Mpad / 64, 512 / 64);            // 314 x 8 = 2512 blocks
    k_gemm64<4, 512, true, true, true><<<g2, 64, 0, stream>>>(
        Acat, Bcat, b1, Hh, N, 512);

    // GEMM3: out = H @ W2^T + b2 (f32). M=20096, N=256, K=512.
    dim3 g3(Mpad / 32, HIDDEN / 64);         // 628 x 4 = 2512 blocks
    k_gemm64<2, 512, false, true, false><<<g3, 64, 0, stream>>>(
        Hh, Wh2, b2, out, N, HIDDEN);
}

// Round 11
// 197.533 us; speedup vs baseline: 1.0526x; 1.0526x over previous
//
#include <hip/hip_runtime.h>

#define HIDDEN 256
#define CAP 64   // bucket capacity per node; deg ~ Poisson(16) => P(deg>=64) ~ e^-40

typedef _Float16 h4_t __attribute__((ext_vector_type(4)));
typedef _Float16 h8_t __attribute__((ext_vector_type(8)));
typedef float    f4_t __attribute__((ext_vector_type(4)));

typedef const __attribute__((address_space(1))) void* gbl_ptr_t;
typedef __attribute__((address_space(3))) void*       lds_ptr_t;

__device__ inline f4_t cvt4(h4_t h) {
    f4_t o; o.x = (float)h.x; o.y = (float)h.y; o.z = (float)h.z; o.w = (float)h.w;
    return o;
}

// ---------------- prep: bucket-fill, weights->f16, mask flags (NO x pass) -----------
__global__ __launch_bounds__(256) void k_prep(
        const int* __restrict__ ei, const int* __restrict__ ea, int E,
        int* __restrict__ cnt, int* __restrict__ csr, int nb_fill,
        const float* __restrict__ W_enc, const float* __restrict__ W1,
        const float* __restrict__ W2, _Float16* __restrict__ Whenc,
        _Float16* __restrict__ Wh1, _Float16* __restrict__ Wh2, int nb_w,
        const int* __restrict__ mask, unsigned char* __restrict__ flags, int NM) {
    int b = blockIdx.x;
    int t = threadIdx.x;
    if (b < nb_fill) {
        int e = b * 256 + t;
        if (e >= E) return;
        int src = ei[e];
        int dst = ei[E + e];
        int combo = ea[2 * e] * 3 + ea[2 * e + 1];     // a1*3+a2, 0..17
        int slot = atomicAdd(&cnt[dst], 1);
        if (slot < CAP) csr[dst * CAP + slot] = src | (combo << 16);
        return;
    }
    b -= nb_fill;
    if (b < nb_w) {
        const int n0 = HIDDEN * HIDDEN, n1 = 2 * HIDDEN * HIDDEN, n2 = HIDDEN * 2 * HIDDEN;
        int base = (b * 256 + t) * 4;
        const float* s; _Float16* d; int off;
        if (base < n0) { s = W_enc; d = Whenc; off = base; }
        else if (base < n0 + n1) { s = W1; d = Wh1; off = base - n0; }
        else if (base < n0 + n1 + n2) { s = W2; d = Wh2; off = base - n0 - n1; }
        else return;
        f4_t v = *(const f4_t*)(s + off);
        h4_t o; o.x = (_Float16)v.x; o.y = (_Float16)v.y;
        o.z = (_Float16)v.z; o.w = (_Float16)v.w;
        *(h4_t*)(d + off) = o;
        return;
    }
    b -= nb_w;
    {
        int i = b * 256 + t;
        if (i < NM) flags[mask[i]] = 1;
    }
}

// ---------------- GEMM1 fused with prelu+cvt: XE = prelu(x) @ Wenc^T, mask-zeroed ----
// 1-wave blocks, tile 32 x 128, K=256, no LDS: A-fragments read directly from fp32
// x (two float4 per frag, affine addresses -> compiler pipelines freely), prelu +
// f16-convert in-register; B-fragments are 16B f16 loads from L2-hot Whenc.
__global__ __launch_bounds__(64) void k_gemm_x(
        const float* __restrict__ x, const _Float16* __restrict__ Wenc,
        const float* __restrict__ prelu_a,
        const unsigned char* __restrict__ flags,
        _Float16* __restrict__ XE, int N) {
    int L = threadIdx.x;
    int m0 = blockIdx.x * 32, n0 = blockIdx.y * 128;
    int lr = L & 15, lk = (L >> 4) * 8;
    float pa = *prelu_a;

    f4_t acc[2][8] = {};
#pragma unroll
    for (int s = 0; s < 8; ++s) {
        h8_t af[2];
#pragma unroll
        for (int i = 0; i < 2; ++i) {
            int row = m0 + i * 16 + lr;
            f4_t v0 = {0.f, 0.f, 0.f, 0.f}, v1 = {0.f, 0.f, 0.f, 0.f};
            if (row < N) {
                const float* ap = x + (size_t)row * HIDDEN + s * 32 + lk;
                v0 = *(const f4_t*)ap;
                v1 = *(const f4_t*)(ap + 4);
            }
            af[i][0] = (_Float16)(v0.x >= 0.f ? v0.x : pa * v0.x);
            af[i][1] = (_Float16)(v0.y >= 0.f ? v0.y : pa * v0.y);
            af[i][2] = (_Float16)(v0.z >= 0.f ? v0.z : pa * v0.z);
            af[i][3] = (_Float16)(v0.w >= 0.f ? v0.w : pa * v0.w);
            af[i][4] = (_Float16)(v1.x >= 0.f ? v1.x : pa * v1.x);
            af[i][5] = (_Float16)(v1.y >= 0.f ? v1.y : pa * v1.y);
            af[i][6] = (_Float16)(v1.z >= 0.f ? v1.z : pa * v1.z);
            af[i][7] = (_Float16)(v1.w >= 0.f ? v1.w : pa * v1.w);
        }
#pragma unroll
        for (int j = 0; j < 8; ++j) {
            h8_t bf = *(const h8_t*)(Wenc + (size_t)(n0 + j * 16 + lr) * HIDDEN + s * 32 + lk);
#pragma unroll
            for (int i = 0; i < 2; ++i)
                acc[i][j] = __builtin_amdgcn_mfma_f32_16x16x32_f16(af[i], bf, acc[i][j], 0, 0, 0);
        }
    }

    // epilogue: C/D layout col = L&15, row = (L>>4)*4 + r; zero masked rows
    int lr4 = (L >> 4) * 4;
#pragma unroll
    for (int i = 0; i < 2; ++i)
#pragma unroll
        for (int r = 0; r < 4; ++r) {
            int row = m0 + i * 16 + lr4 + r;
            float zm = flags[row] ? 0.f : 1.f;
#pragma unroll
            for (int j = 0; j < 8; ++j) {
                int col = n0 + j * 16 + lr;
                XE[(size_t)row * HIDDEN + col] = (_Float16)(acc[i][j][r] * zm);
            }
        }
}

// ---------------- aggregation: 4 nodes / 256-thr block; csr preload + 8-wide gather --
__global__ __launch_bounds__(256) void k_aggregate(
        const _Float16* __restrict__ xe,
        const float* __restrict__ E1, const float* __restrict__ E2,
        const int* __restrict__ cnt, const int* __restrict__ csr,
        _Float16* __restrict__ aggr, int N, int Mpad) {
    __shared__ __align__(16) _Float16 e12h[18 * HIDDEN];   // 9 KB
    int t = threadIdx.x;
    for (int idx = t; idx < 18 * 64; idx += 256) {
        int combo = idx >> 6, c4 = (idx & 63) * 4;
        int a1 = combo / 3, a2 = combo - a1 * 3;
        f4_t v1 = *(const f4_t*)(E1 + a1 * HIDDEN + c4);
        f4_t v2 = *(const f4_t*)(E2 + a2 * HIDDEN + c4);
        h4_t o;
        o.x = (_Float16)(v1.x + v2.x); o.y = (_Float16)(v1.y + v2.y);
        o.z = (_Float16)(v1.z + v2.z); o.w = (_Float16)(v1.w + v2.w);
        *(h4_t*)(e12h + combo * HIDDEN + c4) = o;
    }
    __syncthreads();
    int node = blockIdx.x * 4 + (t >> 6);
    if (node >= Mpad) return;
    int lane = t & 63;
    int c0 = lane * 4;
    if (node >= N) {
        *(h4_t*)(aggr + (size_t)node * HIDDEN + c0) = (h4_t)(_Float16)0.f;
        return;
    }
    int deg = cnt[node];
    if (deg > CAP) deg = CAP;
    const int* lst = csr + (size_t)node * CAP;
    int pv = (lane < deg) ? lst[lane] : 0;        // all edge descriptors, 1 per lane

    h4_t hs = *(const h4_t*)(xe + (size_t)node * HIDDEN + c0);
    h4_t se = *(const h4_t*)(e12h + 12 * HIDDEN + c0);     // self-loop: E1[4]+E2[0]
    f4_t acc = cvt4(hs) + cvt4(se);

    int e = 0;
    for (; e + 7 < deg; e += 8) {
        int p[8]; h4_t hv[8], qv[8];
#pragma unroll
        for (int j = 0; j < 8; ++j) p[j] = __shfl(pv, e + j, 64);
#pragma unroll
        for (int j = 0; j < 8; ++j)
            hv[j] = *(const h4_t*)(xe + (size_t)(p[j] & 0xFFFF) * HIDDEN + c0);
#pragma unroll
        for (int j = 0; j < 8; ++j)
            qv[j] = *(const h4_t*)(e12h + (p[j] >> 16) * HIDDEN + c0);
        h4_t s0 = (hv[0] + qv[0]) + (hv[1] + qv[1]);   // v_pk_add_f16 trees, depth 2
        h4_t s1 = (hv[2] + qv[2]) + (hv[3] + qv[3]);
        h4_t s2 = (hv[4] + qv[4]) + (hv[5] + qv[5]);
        h4_t s3 = (hv[6] + qv[6]) + (hv[7] + qv[7]);
        acc += cvt4(s0) + cvt4(s1);
        acc += cvt4(s2) + cvt4(s3);
    }
    for (; e < deg; ++e) {
        int p = __shfl(pv, e, 64);
        h4_t h = *(const h4_t*)(xe + (size_t)(p & 0xFFFF) * HIDDEN + c0);
        h4_t q = *(const h4_t*)(e12h + (p >> 16) * HIDDEN + c0);
        acc += cvt4(h + q);
    }
    h4_t o;
    o.x = (_Float16)acc.x; o.y = (_Float16)acc.y;
    o.z = (_Float16)acc.z; o.w = (_Float16)acc.w;
    *(h4_t*)(aggr + (size_t)node * HIDDEN + c0) = o;
}

// ---------------- single-wave pipelined MFMA GEMM: C = act(A @ B^T + bias) -----------
// 64-thread (1-wave) blocks, tile BM(=TM*16) x 64, BK=32. Wave-local waitcnt in
// place of barriers; next K-tile's global_load_lds issued before the MFMAs.
template <int TM, int K, bool RELU, bool HAS_BIAS, bool OUT_F16>
__global__ __launch_bounds__(64) void k_gemm64(
        const _Float16* __restrict__ A, const _Float16* __restrict__ B,
        const float* __restrict__ bias, void* __restrict__ Cout,
        int Mstore, int N) {
    constexpr int BM = TM * 16;
    __shared__ __align__(16) _Float16 As[BM * 32];
    __shared__ __align__(16) _Float16 Bs[64 * 32];
    int L = threadIdx.x;
    int m0 = blockIdx.x * BM, n0 = blockIdx.y * 64;
    int lr = L & 15, lk = (L >> 4) * 8;

    f4_t acc[TM][4] = {};

    auto stage = [&](int k0) {
#pragma unroll
        for (int i = 0; i < TM; ++i) {          // A: TM*64 16B chunks
            int c = L + 64 * i;
            __builtin_amdgcn_global_load_lds(
                (gbl_ptr_t)(A + (size_t)(m0 + (c >> 2)) * K + k0 + (c & 3) * 8),
                (lds_ptr_t)(As + c * 8), 16, 0, 0);
        }
#pragma unroll
        for (int i = 0; i < 4; ++i) {           // B: 256 chunks
            int c = L + 64 * i;
            __builtin_amdgcn_global_load_lds(
                (gbl_ptr_t)(B + (size_t)(n0 + (c >> 2)) * K + k0 + (c & 3) * 8),
                (lds_ptr_t)(Bs + c * 8), 16, 0, 0);
        }
    };

    stage(0);
    constexpr int NS = K / 32;
#pragma unroll
    for (int s = 0; s < NS; ++s) {
        asm volatile("s_waitcnt vmcnt(0)" ::: "memory");   // stage(s) landed in LDS
        h8_t af[TM], bf[4];
#pragma unroll
        for (int i = 0; i < TM; ++i) af[i] = *(const h8_t*)&As[(i * 16 + lr) * 32 + lk];
#pragma unroll
        for (int j = 0; j < 4; ++j)  bf[j] = *(const h8_t*)&Bs[(j * 16 + lr) * 32 + lk];
        asm volatile("s_waitcnt lgkmcnt(0)" ::: "memory"); // frags in regs; LDS reusable
        if (s + 1 < NS) stage((s + 1) * 32);               // overlaps MFMAs below
#pragma unroll
        for (int i = 0; i < TM; ++i)
#pragma unroll
            for (int j = 0; j < 4; ++j)
                acc[i][j] = __builtin_amdgcn_mfma_f32_16x16x32_f16(af[i], bf[j], acc[i][j], 0, 0, 0);
    }

    // epilogue: C/D layout col = L&15, row = (L>>4)*4 + r
    int lr4 = (L >> 4) * 4;
#pragma unroll
    for (int i = 0; i < TM; ++i)
#pragma unroll
        for (int r = 0; r < 4; ++r) {
            int row = m0 + i * 16 + lr4 + r;
#pragma unroll
            for (int j = 0; j < 4; ++j) {
                int col = n0 + j * 16 + lr;
                float v = acc[i][j][r];
                if (HAS_BIAS) v += bias[col];
                if (RELU) v = v > 0.f ? v : 0.f;
                if (OUT_F16) {
                    ((_Float16*)Cout)[(size_t)row * N + col] = (_Float16)v;
                } else {
                    if (row < Mstore) ((float*)Cout)[(size_t)row * N + col] = v;
                }
            }
        }
}

extern "C" void kernel_launch(void* const* d_in, const int* in_sizes, int n_in,
                              void* d_out, int out_size, void* d_ws, size_t ws_size,
                              hipStream_t stream) {
    const float* x       = (const float*)d_in[0];
    const int*   ei      = (const int*)d_in[1];
    const int*   ea      = (const int*)d_in[2];
    const int*   mask    = (const int*)d_in[3];
    const float* prelu_a = (const float*)d_in[4];
    const float* W_enc   = (const float*)d_in[5];
    const float* E1      = (const float*)d_in[6];
    const float* E2      = (const float*)d_in[7];
    const float* W1      = (const float*)d_in[8];
    const float* b1      = (const float*)d_in[9];
    const float* W2      = (const float*)d_in[10];
    const float* b2      = (const float*)d_in[11];
    float*       out     = (float*)d_out;

    int N  = in_sizes[0] / HIDDEN;           // 20000
    int E  = in_sizes[1] / 2;                // 320000
    int NM = in_sizes[3];                    // 2000
    int Mpad = ((N + 127) / 128) * 128;      // 20096 (multiple of 32 and 64)

    char* ws = (char*)d_ws;
    size_t off = 0;
    _Float16* XEh   = (_Float16*)(ws + off); off += (size_t)Mpad * HIDDEN * 2;
    _Float16* AGh   = (_Float16*)(ws + off); off += (size_t)Mpad * HIDDEN * 2;
    _Float16* Hh    = (_Float16*)(ws + off); off += (size_t)Mpad * 2 * HIDDEN * 2;
    _Float16* Whenc = (_Float16*)(ws + off); off += (size_t)HIDDEN * HIDDEN * 2;
    _Float16* Wh1   = (_Float16*)(ws + off); off += (size_t)2 * HIDDEN * HIDDEN * 2;
    _Float16* Wh2   = (_Float16*)(ws + off); off += (size_t)HIDDEN * 2 * HIDDEN * 2;
    int* cnt        = (int*)(ws + off);      off += (size_t)N * 4;
    unsigned char* flags = (unsigned char*)(ws + off); off += (size_t)Mpad;
    off = (off + 15) & ~(size_t)15;
    int* csr        = (int*)(ws + off);      off += (size_t)N * CAP * 4;

    hipMemsetAsync(cnt, 0, (size_t)N * 4 + (size_t)Mpad, stream);   // cnt + flags

    int nb_fill = (E + 255) / 256;                   // 1250
    int wtot4   = (HIDDEN * HIDDEN + 2 * HIDDEN * HIDDEN + HIDDEN * 2 * HIDDEN) / 4;
    int nb_w    = (wtot4 + 255) / 256;               // 320
    int nb_m    = (NM + 255) / 256;                  // 8
    k_prep<<<nb_fill + nb_w + nb_m, 256, 0, stream>>>(
        ei, ea, E, cnt, csr, nb_fill,
        W_enc, W1, W2, Whenc, Wh1, Wh2, nb_w,
        mask, flags, NM);

    // GEMM1 fused prelu+cvt: XE = prelu(x)@Wenc^T, masked rows zeroed.
    dim3 g1(Mpad / 32, HIDDEN / 128);        // 628 x 2
    k_gemm_x<<<g1, 64, 0, stream>>>(x, Whenc, prelu_a, flags, XEh, N);

    k_aggregate<<<(Mpad + 3) / 4, 256, 0, stream>>>(XEh, E1, E2, cnt, csr, AGh, N, Mpad);

    // GEMM2: H = relu(AG@W1^T + b1). 64x64 tiles -> 2512 blocks.
    dim3 g2(Mpad / 64, 2 * HIDDEN / 64);
    k_gemm64<4, HIDDEN, true, true, true><<<g2, 64, 0, stream>>>(
        AGh, Wh1, b1, Hh, N, 2 * HIDDEN);

    // GEMM3: out = H@W2^T + b2 (f32). 32x64 tiles -> 2512 blocks.
    dim3 g3(Mpad / 32, HIDDEN / 64);
    k_gemm64<2, 2 * HIDDEN, false, true, false><<<g3, 64, 0, stream>>>(
        Hh, Wh2, b2, out, N, HIDDEN);
}

// Round 12
// 191.076 us; speedup vs baseline: 1.0882x; 1.0338x over previous
//
#include <hip/hip_runtime.h>

#define HIDDEN 256
#define CAP 64   // bucket capacity per node; deg ~ Poisson(16) => P(deg>=64) ~ e^-40

typedef _Float16 h4_t __attribute__((ext_vector_type(4)));
typedef _Float16 h8_t __attribute__((ext_vector_type(8)));
typedef float    f4_t __attribute__((ext_vector_type(4)));

typedef const __attribute__((address_space(1))) void* gbl_ptr_t;
typedef __attribute__((address_space(3))) void*       lds_ptr_t;

__device__ inline f4_t cvt4(h4_t h) {
    f4_t o; o.x = (float)h.x; o.y = (float)h.y; o.z = (float)h.z; o.w = (float)h.w;
    return o;
}

__device__ inline _Float16 prelu_h(float v, float pa) {
    return (_Float16)(v >= 0.f ? v : pa * v);
}

// ---------------- fused prep: x->f16(prelu) [2 float4/thr], edge fill [2 edges/thr],
// ---------------- weights->f16, mask flags ------------------------------------------
__global__ __launch_bounds__(256) void k_prep(
        const float* __restrict__ x, _Float16* __restrict__ xh,
        const float* __restrict__ prelu_a, int M, int Mpad, int nb_x,
        const int* __restrict__ ei, const int* __restrict__ ea, int E,
        int* __restrict__ cnt, int* __restrict__ csr, int nb_fill,
        const float* __restrict__ W_enc, const float* __restrict__ W1,
        const float* __restrict__ W2, _Float16* __restrict__ Whenc,
        _Float16* __restrict__ Wh1, _Float16* __restrict__ Wh2, int nb_w,
        const int* __restrict__ mask, unsigned char* __restrict__ flags, int NM) {
    int b = blockIdx.x;
    int t = threadIdx.x;
    if (b < nb_x) {
        // 32 B of x per thread: two independent float4 loads -> one 16B h8 store
        int base = (b * 256 + t) * 8;
        if (base >= Mpad * HIDDEN) return;
        int row = base >> 8;
        h8_t o;
        if (row < M) {
            float pa = *prelu_a;
            f4_t v0 = *(const f4_t*)(x + base);
            f4_t v1 = *(const f4_t*)(x + base + 4);
            o[0] = prelu_h(v0.x, pa); o[1] = prelu_h(v0.y, pa);
            o[2] = prelu_h(v0.z, pa); o[3] = prelu_h(v0.w, pa);
            o[4] = prelu_h(v1.x, pa); o[5] = prelu_h(v1.y, pa);
            o[6] = prelu_h(v1.z, pa); o[7] = prelu_h(v1.w, pa);
        } else {
            o = (h8_t)(_Float16)0.f;
        }
        *(h8_t*)(xh + base) = o;
        return;
    }
    b -= nb_x;
    if (b < nb_fill) {
        // 2 edges per thread: int2/int4 vector loads, two independent atomic+store chains
        int e0 = (b * 256 + t) * 2;
        if (e0 >= E) return;
        int2 s2 = *(const int2*)(ei + e0);
        int2 d2 = *(const int2*)(ei + E + e0);
        int4 a4 = *(const int4*)(ea + 2 * e0);
        int combo0 = a4.x * 3 + a4.y;                 // a1*3+a2, 0..17
        int combo1 = a4.z * 3 + a4.w;
        int slot0 = atomicAdd(&cnt[d2.x], 1);
        int slot1 = atomicAdd(&cnt[d2.y], 1);
        if (slot0 < CAP) csr[d2.x * CAP + slot0] = s2.x | (combo0 << 16);
        if (slot1 < CAP) csr[d2.y * CAP + slot1] = s2.y | (combo1 << 16);
        return;
    }
    b -= nb_fill;
    if (b < nb_w) {
        const int n0 = HIDDEN * HIDDEN, n1 = 2 * HIDDEN * HIDDEN, n2 = HIDDEN * 2 * HIDDEN;
        int base = (b * 256 + t) * 4;
        const float* s; _Float16* d; int off;
        if (base < n0) { s = W_enc; d = Whenc; off = base; }
        else if (base < n0 + n1) { s = W1; d = Wh1; off = base - n0; }
        else if (base < n0 + n1 + n2) { s = W2; d = Wh2; off = base - n0 - n1; }
        else return;
        f4_t v = *(const f4_t*)(s + off);
        h4_t o; o.x = (_Float16)v.x; o.y = (_Float16)v.y;
        o.z = (_Float16)v.z; o.w = (_Float16)v.w;
        *(h4_t*)(d + off) = o;
        return;
    }
    b -= nb_w;
    {
        int i = b * 256 + t;
        if (i < NM) flags[mask[i]] = 1;
    }
}

// ---------------- aggregation: 4 nodes / 256-thr block; csr preload + 8-wide gather --
__global__ __launch_bounds__(256) void k_aggregate(
        const _Float16* __restrict__ xe,
        const float* __restrict__ E1, const float* __restrict__ E2,
        const int* __restrict__ cnt, const int* __restrict__ csr,
        _Float16* __restrict__ aggr, int N, int Mpad) {
    __shared__ __align__(16) _Float16 e12h[18 * HIDDEN];   // 9 KB
    int t = threadIdx.x;
    for (int idx = t; idx < 18 * 64; idx += 256) {
        int combo = idx >> 6, c4 = (idx & 63) * 4;
        int a1 = combo / 3, a2 = combo - a1 * 3;
        f4_t v1 = *(const f4_t*)(E1 + a1 * HIDDEN + c4);
        f4_t v2 = *(const f4_t*)(E2 + a2 * HIDDEN + c4);
        h4_t o;
        o.x = (_Float16)(v1.x + v2.x); o.y = (_Float16)(v1.y + v2.y);
        o.z = (_Float16)(v1.z + v2.z); o.w = (_Float16)(v1.w + v2.w);
        *(h4_t*)(e12h + combo * HIDDEN + c4) = o;
    }
    __syncthreads();
    int node = blockIdx.x * 4 + (t >> 6);
    if (node >= Mpad) return;
    int lane = t & 63;
    int c0 = lane * 4;
    if (node >= N) {
        *(h4_t*)(aggr + (size_t)node * HIDDEN + c0) = (h4_t)(_Float16)0.f;
        return;
    }
    int deg = cnt[node];
    if (deg > CAP) deg = CAP;
    const int* lst = csr + (size_t)node * CAP;
    int pv = (lane < deg) ? lst[lane] : 0;        // all edge descriptors, 1 per lane

    h4_t hs = *(const h4_t*)(xe + (size_t)node * HIDDEN + c0);
    h4_t se = *(const h4_t*)(e12h + 12 * HIDDEN + c0);     // self-loop: E1[4]+E2[0]
    f4_t acc = cvt4(hs) + cvt4(se);

    int e = 0;
    for (; e + 7 < deg; e += 8) {
        int p[8]; h4_t hv[8], qv[8];
#pragma unroll
        for (int j = 0; j < 8; ++j) p[j] = __shfl(pv, e + j, 64);
#pragma unroll
        for (int j = 0; j < 8; ++j)
            hv[j] = *(const h4_t*)(xe + (size_t)(p[j] & 0xFFFF) * HIDDEN + c0);
#pragma unroll
        for (int j = 0; j < 8; ++j)
            qv[j] = *(const h4_t*)(e12h + (p[j] >> 16) * HIDDEN + c0);
        h4_t s0 = (hv[0] + qv[0]) + (hv[1] + qv[1]);   // v_pk_add_f16 trees, depth 2
        h4_t s1 = (hv[2] + qv[2]) + (hv[3] + qv[3]);
        h4_t s2 = (hv[4] + qv[4]) + (hv[5] + qv[5]);
        h4_t s3 = (hv[6] + qv[6]) + (hv[7] + qv[7]);
        acc += cvt4(s0) + cvt4(s1);
        acc += cvt4(s2) + cvt4(s3);
    }
    for (; e < deg; ++e) {
        int p = __shfl(pv, e, 64);
        h4_t h = *(const h4_t*)(xe + (size_t)(p & 0xFFFF) * HIDDEN + c0);
        h4_t q = *(const h4_t*)(e12h + (p >> 16) * HIDDEN + c0);
        acc += cvt4(h + q);
    }
    h4_t o;
    o.x = (_Float16)acc.x; o.y = (_Float16)acc.y;
    o.z = (_Float16)acc.z; o.w = (_Float16)acc.w;
    *(h4_t*)(aggr + (size_t)node * HIDDEN + c0) = o;
}

// ---------------- single-wave pipelined MFMA GEMM: C = act(A @ B^T + bias) -----------
// 64-thread (1-wave) blocks, tile BM(=TM*16) x 64, BK=32. Wave-local waitcnt in
// place of barriers; next K-tile's global_load_lds issued before the MFMAs.
template <int TM, int K, bool RELU, bool HAS_BIAS, bool OUT_F16, bool MASK>
__global__ __launch_bounds__(64) void k_gemm64(
        const _Float16* __restrict__ A, const _Float16* __restrict__ B,
        const float* __restrict__ bias, void* __restrict__ Cout,
        const unsigned char* __restrict__ flags, int Mstore, int N) {
    constexpr int BM = TM * 16;
    __shared__ __align__(16) _Float16 As[BM * 32];   // BM*64 B
    __shared__ __align__(16) _Float16 Bs[64 * 32];   // 4 KB
    int L = threadIdx.x;
    int m0 = blockIdx.x * BM, n0 = blockIdx.y * 64;
    int lr = L & 15, lk = (L >> 4) * 8;

    f4_t acc[TM][4] = {};

    auto stage = [&](int k0) {
#pragma unroll
        for (int i = 0; i < TM; ++i) {          // A: TM*64 16B chunks
            int c = L + 64 * i;
            __builtin_amdgcn_global_load_lds(
                (gbl_ptr_t)(A + (size_t)(m0 + (c >> 2)) * K + k0 + (c & 3) * 8),
                (lds_ptr_t)(As + c * 8), 16, 0, 0);
        }
#pragma unroll
        for (int i = 0; i < 4; ++i) {           // B: 256 chunks
            int c = L + 64 * i;
            __builtin_amdgcn_global_load_lds(
                (gbl_ptr_t)(B + (size_t)(n0 + (c >> 2)) * K + k0 + (c & 3) * 8),
                (lds_ptr_t)(Bs + c * 8), 16, 0, 0);
        }
    };

    stage(0);
    constexpr int NS = K / 32;
#pragma unroll
    for (int s = 0; s < NS; ++s) {
        asm volatile("s_waitcnt vmcnt(0)" ::: "memory");   // stage(s) landed in LDS
        h8_t af[TM], bf[4];
#pragma unroll
        for (int i = 0; i < TM; ++i) af[i] = *(const h8_t*)&As[(i * 16 + lr) * 32 + lk];
#pragma unroll
        for (int j = 0; j < 4; ++j)  bf[j] = *(const h8_t*)&Bs[(j * 16 + lr) * 32 + lk];
        asm volatile("s_waitcnt lgkmcnt(0)" ::: "memory"); // frags in regs; LDS reusable
        if (s + 1 < NS) stage((s + 1) * 32);               // overlaps MFMAs below
#pragma unroll
        for (int i = 0; i < TM; ++i)
#pragma unroll
            for (int j = 0; j < 4; ++j)
                acc[i][j] = __builtin_amdgcn_mfma_f32_16x16x32_f16(af[i], bf[j], acc[i][j], 0, 0, 0);
    }

    // epilogue: C/D layout col = L&15, row = (L>>4)*4 + r
    int lr4 = (L >> 4) * 4;
#pragma unroll
    for (int i = 0; i < TM; ++i)
#pragma unroll
        for (int r = 0; r < 4; ++r) {
            int row = m0 + i * 16 + lr4 + r;
            float zm = (MASK && flags[row]) ? 0.f : 1.f;
#pragma unroll
            for (int j = 0; j < 4; ++j) {
                int col = n0 + j * 16 + lr;
                float v = acc[i][j][r];
                if (HAS_BIAS) v += bias[col];
                if (RELU) v = v > 0.f ? v : 0.f;
                v *= zm;
                if (OUT_F16) {
                    ((_Float16*)Cout)[(size_t)row * N + col] = (_Float16)v;
                } else {
                    if (row < Mstore) ((float*)Cout)[(size_t)row * N + col] = v;
                }
            }
        }
}

extern "C" void kernel_launch(void* const* d_in, const int* in_sizes, int n_in,
                              void* d_out, int out_size, void* d_ws, size_t ws_size,
                              hipStream_t stream) {
    const float* x       = (const float*)d_in[0];
    const int*   ei      = (const int*)d_in[1];
    const int*   ea      = (const int*)d_in[2];
    const int*   mask    = (const int*)d_in[3];
    const float* prelu_a = (const float*)d_in[4];
    const float* W_enc   = (const float*)d_in[5];
    const float* E1      = (const float*)d_in[6];
    const float* E2      = (const float*)d_in[7];
    const float* W1      = (const float*)d_in[8];
    const float* b1      = (const float*)d_in[9];
    const float* W2      = (const float*)d_in[10];
    const float* b2      = (const float*)d_in[11];
    float*       out     = (float*)d_out;

    int N  = in_sizes[0] / HIDDEN;           // 20000
    int E  = in_sizes[1] / 2;                // 320000
    int NM = in_sizes[3];                    // 2000
    int Mpad = ((N + 127) / 128) * 128;      // 20096 (multiple of 32 and 64)

    char* ws = (char*)d_ws;
    size_t off = 0;
    _Float16* xh    = (_Float16*)(ws + off); off += (size_t)Mpad * HIDDEN * 2;
    _Float16* XEh   = (_Float16*)(ws + off); off += (size_t)Mpad * HIDDEN * 2;
    _Float16* AGh   = (_Float16*)(ws + off); off += (size_t)Mpad * HIDDEN * 2;
    _Float16* Hh    = (_Float16*)(ws + off); off += (size_t)Mpad * 2 * HIDDEN * 2;
    _Float16* Whenc = (_Float16*)(ws + off); off += (size_t)HIDDEN * HIDDEN * 2;
    _Float16* Wh1   = (_Float16*)(ws + off); off += (size_t)2 * HIDDEN * HIDDEN * 2;
    _Float16* Wh2   = (_Float16*)(ws + off); off += (size_t)HIDDEN * 2 * HIDDEN * 2;
    int* cnt        = (int*)(ws + off);      off += (size_t)N * 4;
    unsigned char* flags = (unsigned char*)(ws + off); off += (size_t)Mpad;
    off = (off + 15) & ~(size_t)15;
    int* csr        = (int*)(ws + off);      off += (size_t)N * CAP * 4;

    hipMemsetAsync(cnt, 0, (size_t)N * 4 + (size_t)Mpad, stream);   // cnt + flags

    int nb_x    = (Mpad * HIDDEN / 8 + 255) / 256;   // 2512  (32 B per thread)
    int nb_fill = (E / 2 + 255) / 256;               // 625   (2 edges per thread)
    int wtot4   = (HIDDEN * HIDDEN + 2 * HIDDEN * HIDDEN + HIDDEN * 2 * HIDDEN) / 4;
    int nb_w    = (wtot4 + 255) / 256;               // 320
    int nb_m    = (NM + 255) / 256;                  // 8
    k_prep<<<nb_x + nb_fill + nb_w + nb_m, 256, 0, stream>>>(
        x, xh, prelu_a, N, Mpad, nb_x,
        ei, ea, E, cnt, csr, nb_fill,
        W_enc, W1, W2, Whenc, Wh1, Wh2, nb_w,
        mask, flags, NM);

    // GEMM1: XE = (prelu(x)@W_enc^T), masked rows zeroed. 32x64 tiles -> 2512 blocks.
    dim3 g1(Mpad / 32, HIDDEN / 64);
    k_gemm64<2, HIDDEN, false, false, true, true><<<g1, 64, 0, stream>>>(
        xh, Whenc, nullptr, XEh, flags, N, HIDDEN);

    k_aggregate<<<(Mpad + 3) / 4, 256, 0, stream>>>(XEh, E1, E2, cnt, csr, AGh, N, Mpad);

    // GEMM2: H = relu(AG@W1^T + b1). 64x64 tiles -> 2512 blocks.
    dim3 g2(Mpad / 64, 2 * HIDDEN / 64);
    k_gemm64<4, HIDDEN, true, true, true, false><<<g2, 64, 0, stream>>>(
        AGh, Wh1, b1, Hh, nullptr, N, 2 * HIDDEN);

    // GEMM3: out = H@W2^T + b2 (f32). 32x64 tiles -> 2512 blocks.
    dim3 g3(Mpad / 32, HIDDEN / 64);
    k_gemm64<2, 2 * HIDDEN, false, true, false, false><<<g3, 64, 0, stream>>>(
        Hh, Wh2, b2, out, nullptr, N, HIDDEN);
}

// Round 13
// 184.595 us; speedup vs baseline: 1.1264x; 1.0351x over previous
//
#include <hip/hip_runtime.h>

#define HIDDEN 256
#define CAP 64   // bucket capacity per node; deg ~ Poisson(16) => P(deg>=64) ~ e^-40

typedef _Float16 h4_t __attribute__((ext_vector_type(4)));
typedef _Float16 h8_t __attribute__((ext_vector_type(8)));
typedef float    f4_t __attribute__((ext_vector_type(4)));

typedef const __attribute__((address_space(1))) void* gbl_ptr_t;
typedef __attribute__((address_space(3))) void*       lds_ptr_t;

__device__ inline f4_t cvt4(h4_t h) {
    f4_t o; o.x = (float)h.x; o.y = (float)h.y; o.z = (float)h.z; o.w = (float)h.w;
    return o;
}

// ---------------- fused prep: x->f16(prelu), weights->f16, bucket-fill, mask flags ----
__global__ __launch_bounds__(256) void k_prep(
        const float* __restrict__ x, _Float16* __restrict__ xh,
        const float* __restrict__ prelu_a, int M, int Mpad, int nb_x,
        const int* __restrict__ ei, const int* __restrict__ ea, int E,
        int* __restrict__ cnt, int* __restrict__ csr, int nb_fill,
        const float* __restrict__ W_enc, const float* __restrict__ W1,
        const float* __restrict__ W2, _Float16* __restrict__ Whenc,
        _Float16* __restrict__ Wh1, _Float16* __restrict__ Wh2, int nb_w,
        const int* __restrict__ mask, unsigned char* __restrict__ flags, int NM) {
    int b = blockIdx.x;
    int t = threadIdx.x;
    if (b < nb_x) {
        int base = (b * 256 + t) * 4;
        if (base >= Mpad * HIDDEN) return;
        int row = base >> 8;
        h4_t o;
        if (row < M) {
            float pa = *prelu_a;
            f4_t v = *(const f4_t*)(x + base);
            o.x = (_Float16)(v.x >= 0.f ? v.x : pa * v.x);
            o.y = (_Float16)(v.y >= 0.f ? v.y : pa * v.y);
            o.z = (_Float16)(v.z >= 0.f ? v.z : pa * v.z);
            o.w = (_Float16)(v.w >= 0.f ? v.w : pa * v.w);
        } else {
            o = (h4_t)(_Float16)0.f;
        }
        *(h4_t*)(xh + base) = o;
        return;
    }
    b -= nb_x;
    if (b < nb_fill) {
        int e = b * 256 + t;
        if (e >= E) return;
        int src = ei[e];
        int dst = ei[E + e];
        int combo = ea[2 * e] * 3 + ea[2 * e + 1];     // a1*3+a2, 0..17
        int slot = atomicAdd(&cnt[dst], 1);
        if (slot < CAP) csr[dst * CAP + slot] = src | (combo << 16);
        return;
    }
    b -= nb_fill;
    if (b < nb_w) {
        const int n0 = HIDDEN * HIDDEN, n1 = 2 * HIDDEN * HIDDEN, n2 = HIDDEN * 2 * HIDDEN;
        int base = (b * 256 + t) * 4;
        const float* s; _Float16* d; int off;
        if (base < n0) { s = W_enc; d = Whenc; off = base; }
        else if (base < n0 + n1) { s = W1; d = Wh1; off = base - n0; }
        else if (base < n0 + n1 + n2) { s = W2; d = Wh2; off = base - n0 - n1; }
        else return;
        f4_t v = *(const f4_t*)(s + off);
        h4_t o; o.x = (_Float16)v.x; o.y = (_Float16)v.y;
        o.z = (_Float16)v.z; o.w = (_Float16)v.w;
        *(h4_t*)(d + off) = o;
        return;
    }
    b -= nb_w;
    {
        int i = b * 256 + t;
        if (i < NM) flags[mask[i]] = 1;
    }
}

// ---------------- aggregation: 4 nodes / 256-thr block; csr preload + 8-wide gather --
__global__ __launch_bounds__(256) void k_aggregate(
        const _Float16* __restrict__ xe,
        const float* __restrict__ E1, const float* __restrict__ E2,
        const int* __restrict__ cnt, const int* __restrict__ csr,
        _Float16* __restrict__ aggr, int N, int Mpad) {
    __shared__ __align__(16) _Float16 e12h[18 * HIDDEN];   // 9 KB
    int t = threadIdx.x;
    for (int idx = t; idx < 18 * 64; idx += 256) {
        int combo = idx >> 6, c4 = (idx & 63) * 4;
        int a1 = combo / 3, a2 = combo - a1 * 3;
        f4_t v1 = *(const f4_t*)(E1 + a1 * HIDDEN + c4);
        f4_t v2 = *(const f4_t*)(E2 + a2 * HIDDEN + c4);
        h4_t o;
        o.x = (_Float16)(v1.x + v2.x); o.y = (_Float16)(v1.y + v2.y);
        o.z = (_Float16)(v1.z + v2.z); o.w = (_Float16)(v1.w + v2.w);
        *(h4_t*)(e12h + combo * HIDDEN + c4) = o;
    }
    __syncthreads();
    int node = blockIdx.x * 4 + (t >> 6);
    if (node >= Mpad) return;
    int lane = t & 63;
    int c0 = lane * 4;
    if (node >= N) {
        *(h4_t*)(aggr + (size_t)node * HIDDEN + c0) = (h4_t)(_Float16)0.f;
        return;
    }
    int deg = cnt[node];
    if (deg > CAP) deg = CAP;
    const int* lst = csr + (size_t)node * CAP;
    int pv = (lane < deg) ? lst[lane] : 0;        // all edge descriptors, 1 per lane

    h4_t hs = *(const h4_t*)(xe + (size_t)node * HIDDEN + c0);
    h4_t se = *(const h4_t*)(e12h + 12 * HIDDEN + c0);     // self-loop: E1[4]+E2[0]
    f4_t acc = cvt4(hs) + cvt4(se);

    int e = 0;
    for (; e + 7 < deg; e += 8) {
        int p[8]; h4_t hv[8], qv[8];
#pragma unroll
        for (int j = 0; j < 8; ++j) p[j] = __shfl(pv, e + j, 64);
#pragma unroll
        for (int j = 0; j < 8; ++j)
            hv[j] = *(const h4_t*)(xe + (size_t)(p[j] & 0xFFFF) * HIDDEN + c0);
#pragma unroll
        for (int j = 0; j < 8; ++j)
            qv[j] = *(const h4_t*)(e12h + (p[j] >> 16) * HIDDEN + c0);
        h4_t s0 = (hv[0] + qv[0]) + (hv[1] + qv[1]);   // v_pk_add_f16 trees, depth 2
        h4_t s1 = (hv[2] + qv[2]) + (hv[3] + qv[3]);
        h4_t s2 = (hv[4] + qv[4]) + (hv[5] + qv[5]);
        h4_t s3 = (hv[6] + qv[6]) + (hv[7] + qv[7]);
        acc += cvt4(s0) + cvt4(s1);
        acc += cvt4(s2) + cvt4(s3);
    }
    for (; e < deg; ++e) {
        int p = __shfl(pv, e, 64);
        h4_t h = *(const h4_t*)(xe + (size_t)(p & 0xFFFF) * HIDDEN + c0);
        h4_t q = *(const h4_t*)(e12h + (p >> 16) * HIDDEN + c0);
        acc += cvt4(h + q);
    }
    h4_t o;
    o.x = (_Float16)acc.x; o.y = (_Float16)acc.y;
    o.z = (_Float16)acc.z; o.w = (_Float16)acc.w;
    *(h4_t*)(aggr + (size_t)node * HIDDEN + c0) = o;
}

// ---------------- single-wave pipelined MFMA GEMM: C = act(A @ B^T + bias) -----------
// 64-thread (1-wave) blocks, tile BM(=TM*16) x BN(=TN*16), BK=32. Wave-local
// waitcnt in place of barriers; next K-tile's global_load_lds issued before the
// MFMAs. TN=8 halves A re-reads vs TN=4 and doubles MFMA per staging step.
template <int TM, int TN, int K, bool RELU, bool HAS_BIAS, bool OUT_F16, bool MASK>
__global__ __launch_bounds__(64) void k_gemm64(
        const _Float16* __restrict__ A, const _Float16* __restrict__ B,
        const float* __restrict__ bias, void* __restrict__ Cout,
        const unsigned char* __restrict__ flags, int Mstore, int N) {
    constexpr int BM = TM * 16, BN = TN * 16;
    __shared__ __align__(16) _Float16 As[BM * 32];   // BM*64 B
    __shared__ __align__(16) _Float16 Bs[BN * 32];   // BN*64 B
    int L = threadIdx.x;
    int m0 = blockIdx.x * BM, n0 = blockIdx.y * BN;
    int lr = L & 15, lk = (L >> 4) * 8;

    f4_t acc[TM][TN] = {};

    auto stage = [&](int k0) {
#pragma unroll
        for (int i = 0; i < TM; ++i) {          // A: TM*64 16B chunks
            int c = L + 64 * i;
            __builtin_amdgcn_global_load_lds(
                (gbl_ptr_t)(A + (size_t)(m0 + (c >> 2)) * K + k0 + (c & 3) * 8),
                (lds_ptr_t)(As + c * 8), 16, 0, 0);
        }
#pragma unroll
        for (int i = 0; i < TN; ++i) {          // B: TN*64 chunks
            int c = L + 64 * i;
            __builtin_amdgcn_global_load_lds(
                (gbl_ptr_t)(B + (size_t)(n0 + (c >> 2)) * K + k0 + (c & 3) * 8),
                (lds_ptr_t)(Bs + c * 8), 16, 0, 0);
        }
    };

    stage(0);
    constexpr int NS = K / 32;
#pragma unroll
    for (int s = 0; s < NS; ++s) {
        asm volatile("s_waitcnt vmcnt(0)" ::: "memory");   // stage(s) landed in LDS
        h8_t af[TM], bf[TN];
#pragma unroll
        for (int i = 0; i < TM; ++i) af[i] = *(const h8_t*)&As[(i * 16 + lr) * 32 + lk];
#pragma unroll
        for (int j = 0; j < TN; ++j) bf[j] = *(const h8_t*)&Bs[(j * 16 + lr) * 32 + lk];
        asm volatile("s_waitcnt lgkmcnt(0)" ::: "memory"); // frags in regs; LDS reusable
        if (s + 1 < NS) stage((s + 1) * 32);               // overlaps MFMAs below
#pragma unroll
        for (int i = 0; i < TM; ++i)
#pragma unroll
            for (int j = 0; j < TN; ++j)
                acc[i][j] = __builtin_amdgcn_mfma_f32_16x16x32_f16(af[i], bf[j], acc[i][j], 0, 0, 0);
    }

    // epilogue: C/D layout col = L&15, row = (L>>4)*4 + r
    int lr4 = (L >> 4) * 4;
#pragma unroll
    for (int i = 0; i < TM; ++i)
#pragma unroll
        for (int r = 0; r < 4; ++r) {
            int row = m0 + i * 16 + lr4 + r;
            float zm = (MASK && flags[row]) ? 0.f : 1.f;
#pragma unroll
            for (int j = 0; j < TN; ++j) {
                int col = n0 + j * 16 + lr;
                float v = acc[i][j][r];
                if (HAS_BIAS) v += bias[col];
                if (RELU) v = v > 0.f ? v : 0.f;
                v *= zm;
                if (OUT_F16) {
                    ((_Float16*)Cout)[(size_t)row * N + col] = (_Float16)v;
                } else {
                    if (row < Mstore) ((float*)Cout)[(size_t)row * N + col] = v;
                }
            }
        }
}

extern "C" void kernel_launch(void* const* d_in, const int* in_sizes, int n_in,
                              void* d_out, int out_size, void* d_ws, size_t ws_size,
                              hipStream_t stream) {
    const float* x       = (const float*)d_in[0];
    const int*   ei      = (const int*)d_in[1];
    const int*   ea      = (const int*)d_in[2];
    const int*   mask    = (const int*)d_in[3];
    const float* prelu_a = (const float*)d_in[4];
    const float* W_enc   = (const float*)d_in[5];
    const float* E1      = (const float*)d_in[6];
    const float* E2      = (const float*)d_in[7];
    const float* W1      = (const float*)d_in[8];
    const float* b1      = (const float*)d_in[9];
    const float* W2      = (const float*)d_in[10];
    const float* b2      = (const float*)d_in[11];
    float*       out     = (float*)d_out;

    int N  = in_sizes[0] / HIDDEN;           // 20000
    int E  = in_sizes[1] / 2;                // 320000
    int NM = in_sizes[3];                    // 2000
    int Mpad = ((N + 127) / 128) * 128;      // 20096 (multiple of 32 and 64)

    char* ws = (char*)d_ws;
    size_t off = 0;
    _Float16* xh    = (_Float16*)(ws + off); off += (size_t)Mpad * HIDDEN * 2;
    _Float16* XEh   = (_Float16*)(ws + off); off += (size_t)Mpad * HIDDEN * 2;
    _Float16* AGh   = (_Float16*)(ws + off); off += (size_t)Mpad * HIDDEN * 2;
    _Float16* Hh    = (_Float16*)(ws + off); off += (size_t)Mpad * 2 * HIDDEN * 2;
    _Float16* Whenc = (_Float16*)(ws + off); off += (size_t)HIDDEN * HIDDEN * 2;
    _Float16* Wh1   = (_Float16*)(ws + off); off += (size_t)2 * HIDDEN * HIDDEN * 2;
    _Float16* Wh2   = (_Float16*)(ws + off); off += (size_t)HIDDEN * 2 * HIDDEN * 2;
    int* cnt        = (int*)(ws + off);      off += (size_t)N * 4;
    unsigned char* flags = (unsigned char*)(ws + off); off += (size_t)Mpad;
    off = (off + 15) & ~(size_t)15;
    int* csr        = (int*)(ws + off);      off += (size_t)N * CAP * 4;

    hipMemsetAsync(cnt, 0, (size_t)N * 4 + (size_t)Mpad, stream);   // cnt + flags

    int nb_x    = (Mpad * HIDDEN / 4 + 255) / 256;   // 5024
    int nb_fill = (E + 255) / 256;                   // 1250
    int wtot4   = (HIDDEN * HIDDEN + 2 * HIDDEN * HIDDEN + HIDDEN * 2 * HIDDEN) / 4;
    int nb_w    = (wtot4 + 255) / 256;               // 320
    int nb_m    = (NM + 255) / 256;                  // 8
    k_prep<<<nb_x + nb_fill + nb_w + nb_m, 256, 0, stream>>>(
        x, xh, prelu_a, N, Mpad, nb_x,
        ei, ea, E, cnt, csr, nb_fill,
        W_enc, W1, W2, Whenc, Wh1, Wh2, nb_w,
        mask, flags, NM);

    // GEMM1: XE = (prelu(x)@W_enc^T), masked rows zeroed. 32x128 tiles -> 1256 blocks.
    dim3 g1(Mpad / 32, HIDDEN / 128);
    k_gemm64<2, 8, HIDDEN, false, false, true, true><<<g1, 64, 0, stream>>>(
        xh, Whenc, nullptr, XEh, flags, N, HIDDEN);

    k_aggregate<<<(Mpad + 3) / 4, 256, 0, stream>>>(XEh, E1, E2, cnt, csr, AGh, N, Mpad);

    // GEMM2: H = relu(AG@W1^T + b1). 64x128 tiles -> 1256 blocks.
    dim3 g2(Mpad / 64, 2 * HIDDEN / 128);
    k_gemm64<4, 8, HIDDEN, true, true, true, false><<<g2, 64, 0, stream>>>(
        AGh, Wh1, b1, Hh, nullptr, N, 2 * HIDDEN);

    // GEMM3: out = H@W2^T + b2 (f32). 32x128 tiles -> 1256 blocks.
    dim3 g3(Mpad / 32, HIDDEN / 128);
    k_gemm64<2, 8, 2 * HIDDEN, false, true, false, false><<<g3, 64, 0, stream>>>(
        Hh, Wh2, b2, out, nullptr, N, HIDDEN);
}